// Round 1
// baseline (14211.259 us; speedup 1.0000x reference)
//
#include <hip/hip_runtime.h>

#define N_PTS 16384
#define ROWF  131        // 3 coords + 128 features
#define M_OUT 4096       // N / POOL
#define KNN   16

// ---------------------------------------------------------------------------
// Stage 1: Furthest-point sampling. Single block, 1024 threads, 16 pts/thread.
// All state (coords, min_d2) in registers. Bitwise-exact d2 vs numpy:
// no fma contraction, sum order (dx2+dy2)+dz2. Argmax ties -> lowest index.
// Also extracts dense coords (N,3) and query coords (M,3) into workspace.
// ---------------------------------------------------------------------------
__global__ __launch_bounds__(1024, 4)
void fps_kernel(const float* __restrict__ x, float* __restrict__ out,
                float* __restrict__ coords, float* __restrict__ qcoords)
{
    const int tid = threadIdx.x;

    float cx[16], cy[16], cz[16], md[16];
#pragma unroll
    for (int j = 0; j < 16; ++j) {
        const int p = tid + (j << 10);           // stride-1024 point layout
        const float a = x[p * ROWF + 0];
        const float b = x[p * ROWF + 1];
        const float c = x[p * ROWF + 2];
        cx[j] = a; cy[j] = b; cz[j] = c;
        coords[p * 3 + 0] = a;
        coords[p * 3 + 1] = b;
        coords[p * 3 + 2] = c;
        md[j] = __int_as_float(0x7f800000);      // +inf
    }

    __shared__ float s_wmax[16];
    __shared__ float s_bmax;
    __shared__ int   s_barg;

    __syncthreads();                             // dense coords visible block-wide

    // sample 0 = point 0 (deterministic start)
    float lx = coords[0], ly = coords[1], lz = coords[2];
    if (tid == 0) {
        out[0] = lx; out[1] = ly; out[2] = lz;
        qcoords[0] = lx; qcoords[1] = ly; qcoords[2] = lz;
    }

    for (int s = 1; s < M_OUT; ++s) {
        // ---- update min_d2 with distance to `last`, track thread-local max
        float m = -1.0f;
#pragma unroll
        for (int j = 0; j < 16; ++j) {
            const float dx = cx[j] - lx;
            const float dy = cy[j] - ly;
            const float dz = cz[j] - lz;
            const float d2 = __fadd_rn(__fadd_rn(__fmul_rn(dx, dx),
                                                 __fmul_rn(dy, dy)),
                                       __fmul_rn(dz, dz));
            const float nm = fminf(md[j], d2);
            md[j] = nm;
            m = fmaxf(m, nm);
        }
        // ---- wave max (value only)
#pragma unroll
        for (int off = 32; off; off >>= 1)
            m = fmaxf(m, __shfl_xor(m, off));
        if ((tid & 63) == 0) s_wmax[tid >> 6] = m;
        __syncthreads();                         // [A]
        if (tid == 0) {
            float bm = s_wmax[0];
#pragma unroll
            for (int w = 1; w < 16; ++w) bm = fmaxf(bm, s_wmax[w]);
            s_bmax = bm;
            s_barg = 0x7fffffff;                 // reset here: between [A] and [B]
        }
        __syncthreads();                         // [B]
        const float bm = s_bmax;
        // ---- only waves holding the block max scan for the index (tie -> min idx)
        if (m == bm) {
            int cand = 0x7fffffff;
#pragma unroll
            for (int j = 0; j < 16; ++j)
                if (md[j] == bm) cand = min(cand, tid + (j << 10));
            atomicMin(&s_barg, cand);
        }
        __syncthreads();                         // [C]
        const int nxt = s_barg;
        lx = coords[nxt * 3 + 0];                // uniform address, L1 broadcast
        ly = coords[nxt * 3 + 1];
        lz = coords[nxt * 3 + 2];
        if (tid == 0) {
            float* orow = out + s * ROWF;
            orow[0] = lx; orow[1] = ly; orow[2] = lz;
            qcoords[s * 3 + 0] = lx;
            qcoords[s * 3 + 1] = ly;
            qcoords[s * 3 + 2] = lz;
        }
    }
}

// ---------------------------------------------------------------------------
// Stage 2+3: brute-force KNN (top-16 smallest d2, ties -> lowest index) fused
// with feature max-pool. One wave per query (4 waves / 256-thread block).
// Per-lane sorted top-16 kept as packed u64 (d2_bits<<32 | idx): unsigned
// compare == lexicographic (d2, idx) since d2 >= 0.
// ---------------------------------------------------------------------------
__global__ __launch_bounds__(256)
void knn_pool_kernel(const float* __restrict__ x, const float* __restrict__ coords,
                     const float* __restrict__ qcoords, float* __restrict__ out)
{
    const int lane = threadIdx.x & 63;
    const int q = blockIdx.x * 4 + (threadIdx.x >> 6);

    const float qx = qcoords[q * 3 + 0];
    const float qy = qcoords[q * 3 + 1];
    const float qz = qcoords[q * 3 + 2];

    unsigned long long h[KNN];
#pragma unroll
    for (int k = 0; k < KNN; ++k) h[k] = ~0ULL;

    for (int c = lane; c < N_PTS; c += 64) {
        const float dx = coords[c * 3 + 0] - qx;
        const float dy = coords[c * 3 + 1] - qy;
        const float dz = coords[c * 3 + 2] - qz;
        const float d2 = __fadd_rn(__fadd_rn(__fmul_rn(dx, dx),
                                             __fmul_rn(dy, dy)),
                                   __fmul_rn(dz, dz));
        const unsigned long long e =
            ((unsigned long long)__float_as_uint(d2) << 32) | (unsigned)c;
        if (e < h[KNN - 1]) {                    // beats current 16th -> insert
#pragma unroll
            for (int k = KNN - 1; k >= 1; --k) {
                const unsigned long long prev = h[k - 1];   // old value (desc order)
                h[k] = (e < prev) ? prev : ((e < h[k]) ? e : h[k]);
            }
            h[0] = (e < h[0]) ? e : h[0];
        }
    }

    // ---- merge 64 sorted lists -> global top-16 via repeated wave-min extract
    int nbr[KNN];
#pragma unroll
    for (int r = 0; r < KNN; ++r) {
        unsigned long long best = h[0];
#pragma unroll
        for (int off = 32; off; off >>= 1) {
            const unsigned long long o = __shfl_xor(best, off);
            best = (o < best) ? o : best;
        }
        nbr[r] = (int)(unsigned)(best & 0xffffffffULL);
        if (h[0] == best) {                      // exactly one lane (idx unique)
#pragma unroll
            for (int k = 0; k < KNN - 1; ++k) h[k] = h[k + 1];
            h[KNN - 1] = ~0ULL;
        }
    }

    // ---- feature max-pool: lane = feature column (0..63, 64..127), coalesced
    float a0 = __int_as_float(0xff800000);       // -inf
    float a1 = a0;
#pragma unroll
    for (int r = 0; r < KNN; ++r) {
        const float* row = x + nbr[r] * ROWF + 3;
        a0 = fmaxf(a0, row[lane]);
        a1 = fmaxf(a1, row[lane + 64]);
    }
    float* orow = out + q * ROWF + 3;
    orow[lane]      = a0;
    orow[lane + 64] = a1;
}

extern "C" void kernel_launch(void* const* d_in, const int* in_sizes, int n_in,
                              void* d_out, int out_size, void* d_ws, size_t ws_size,
                              hipStream_t stream) {
    const float* x = (const float*)d_in[0];
    float* out = (float*)d_out;
    float* coords  = (float*)d_ws;               // N*3 floats
    float* qcoords = coords + N_PTS * 3;         // M*3 floats

    hipLaunchKernelGGL(fps_kernel, dim3(1), dim3(1024), 0, stream,
                       x, out, coords, qcoords);
    hipLaunchKernelGGL(knn_pool_kernel, dim3(M_OUT / 4), dim3(256), 0, stream,
                       x, coords, qcoords, out);
}

// Round 2
// 11898.518 us; speedup vs baseline: 1.1944x; 1.1944x over previous
//
#include <hip/hip_runtime.h>

#define N_PTS 16384
#define ROWF  131        // 3 coords + 128 features
#define M_OUT 4096       // N / POOL
#define KNN   16
#define FPS_T 512        // fps threads (8 waves)
#define CHUNK 32         // points per fps thread
#define SORT_T 1024

typedef unsigned long long u64;

// spread 4 bits -> every 3rd bit (Morton interleave LUT)
__device__ __constant__ unsigned short c_spread4[16] =
  {0,1,8,9,64,65,72,73,512,513,520,521,576,577,584,585};

__device__ __forceinline__ int cell_of(float x, float y, float z) {
  int ix = (int)floorf((x + 4.0f) * 2.0f); ix = ix < 0 ? 0 : (ix > 15 ? 15 : ix);
  int iy = (int)floorf((y + 4.0f) * 2.0f); iy = iy < 0 ? 0 : (iy > 15 ? 15 : iy);
  int iz = (int)floorf((z + 4.0f) * 2.0f); iz = iz < 0 ? 0 : (iz > 15 ? 15 : iz);
  return (int)c_spread4[ix] | ((int)c_spread4[iy] << 1) | ((int)c_spread4[iz] << 2);
}

// ---------------------------------------------------------------------------
// 1) Extract coords into SoA (orig-index order) for winner lookup + knn.
// ---------------------------------------------------------------------------
__global__ void prep_kernel(const float* __restrict__ x,
                            float* __restrict__ cX, float* __restrict__ cY,
                            float* __restrict__ cZ) {
  const int p = blockIdx.x * blockDim.x + threadIdx.x;
  if (p < N_PTS) {
    cX[p] = x[p * ROWF + 0];
    cY[p] = x[p * ROWF + 1];
    cZ[p] = x[p * ROWF + 2];
  }
}

// ---------------------------------------------------------------------------
// 2) Counting-sort by Morton cell (4096 cells), one 1024-thread block.
//    Produces spatially-sorted gX/gY/gZ/gIdx. Scatter order within a cell is
//    racy but output-invariant (all downstream math keyed by original index).
// ---------------------------------------------------------------------------
__global__ __launch_bounds__(1024, 1)
void sort_kernel(const float* __restrict__ cX, const float* __restrict__ cY,
                 const float* __restrict__ cZ,
                 float* __restrict__ gX, float* __restrict__ gY,
                 float* __restrict__ gZ, int* __restrict__ gIdx) {
  __shared__ unsigned int sh[4096];
  __shared__ unsigned int sws[16];
  const int tid = threadIdx.x, lane = tid & 63, wid = tid >> 6;

#pragma unroll
  for (int i = 0; i < 4; ++i) sh[tid * 4 + i] = 0;
  __syncthreads();

  int cel[16];
#pragma unroll
  for (int j = 0; j < 16; ++j) {
    const int p = tid + SORT_T * j;
    const int c = cell_of(cX[p], cY[p], cZ[p]);
    cel[j] = c;
    atomicAdd(&sh[c], 1u);
  }
  __syncthreads();

  // prefix sum over 4096 counts (4 per thread)
  const unsigned h0 = sh[tid * 4 + 0], h1 = sh[tid * 4 + 1];
  const unsigned h2 = sh[tid * 4 + 2], h3 = sh[tid * 4 + 3];
  const unsigned tsum = h0 + h1 + h2 + h3;
  unsigned inc = tsum;
#pragma unroll
  for (int off = 1; off < 64; off <<= 1) {
    const unsigned v = __shfl_up(inc, off);
    if (lane >= off) inc += v;
  }
  if (lane == 63) sws[wid] = inc;
  __syncthreads();
  if (tid == 0) {
    unsigned run = 0;
#pragma unroll
    for (int w = 0; w < 16; ++w) { const unsigned t = sws[w]; sws[w] = run; run += t; }
  }
  __syncthreads();
  const unsigned base = sws[wid] + inc - tsum;
  sh[tid * 4 + 0] = base;
  sh[tid * 4 + 1] = base + h0;
  sh[tid * 4 + 2] = base + h0 + h1;
  sh[tid * 4 + 3] = base + h0 + h1 + h2;
  __syncthreads();

#pragma unroll
  for (int j = 0; j < 16; ++j) {
    const int p = tid + SORT_T * j;
    const unsigned pos = atomicAdd(&sh[cel[j]], 1u);
    gX[pos] = cX[p]; gY[pos] = cY[p]; gZ[pos] = cZ[p]; gIdx[pos] = p;
  }
}

// ---------------------------------------------------------------------------
// 3) FPS with exact triangle-inequality chunk pruning.
//    512 threads, 32 sorted pts/chunk. min_d2 in LDS (transposed, conflict-
//    free). Persistent regs/thread ~12. Skips are PROVABLY no-op updates ->
//    md trajectory bitwise identical to the unpruned reference.
//    Key = (md_bits<<32) | (N-1-orig_idx): max -> max md, tie -> lowest idx.
// ---------------------------------------------------------------------------
__global__ __launch_bounds__(FPS_T, 1)
void fps_kernel(const float* __restrict__ cX, const float* __restrict__ cY,
                const float* __restrict__ cZ,
                const float* __restrict__ gX, const float* __restrict__ gY,
                const float* __restrict__ gZ, const int* __restrict__ gIdx,
                float* __restrict__ out, float* __restrict__ qc) {
  __shared__ float smd[N_PTS];          // slot (j*FPS_T + tid): lanes stride-1
  __shared__ u64 s_wkey[8];

  const int tid = threadIdx.x, lane = tid & 63;
  const int base = tid * CHUNK;

  // chunk bounding sphere (any center works; r must upper-bound member dist)
  float sx = 0.f, sy = 0.f, sz = 0.f;
#pragma unroll 4
  for (int j = 0; j < CHUNK; ++j) {
    sx += gX[base + j]; sy += gY[base + j]; sz += gZ[base + j];
    smd[j * FPS_T + tid] = __int_as_float(0x7f800000);  // +inf
  }
  const float mx = sx * (1.0f / CHUNK), my = sy * (1.0f / CHUNK), mz = sz * (1.0f / CHUNK);
  float r2 = 0.f;
#pragma unroll 4
  for (int j = 0; j < CHUNK; ++j) {
    const float dx = gX[base + j] - mx, dy = gY[base + j] - my, dz = gZ[base + j] - mz;
    r2 = fmaxf(r2, dx * dx + dy * dy + dz * dz);
  }
  const float r = sqrtf(r2) * 1.000001f + 1e-6f;

  float cmax = __int_as_float(0x7f800000);
  u64 ckey = 0;

  float qx = cX[0], qy = cY[0], qz = cZ[0];
  if (tid == 0) {
    out[0] = qx; out[1] = qy; out[2] = qz;
    qc[0] = qx; qc[1] = qy; qc[2] = qz;
  }
  __syncthreads();

  for (int s = 1; s < M_OUT; ++s) {
    // conservative prune test (margins make skip => provably no member changes)
    const float ddx = mx - qx, ddy = my - qy, ddz = mz - qz;
    const float dd = ddx * ddx + ddy * ddy + ddz * ddz;
    const float lb = sqrtf(dd) * 0.999999f - r;
    const bool skip = (lb > 0.f) && (lb * lb >= cmax * 1.0001f + 1e-12f);

    if (!skip) {
      u64 nk = 0;
#pragma unroll
      for (int g = 0; g < CHUNK / 4; ++g) {
        const float4 vx = *(const float4*)(gX + base + g * 4);
        const float4 vy = *(const float4*)(gY + base + g * 4);
        const float4 vz = *(const float4*)(gZ + base + g * 4);
        const int4  vi = *(const int4*)(gIdx + base + g * 4);
#define FPS_UPD(E, Eoff)                                                        \
        {                                                                       \
          const int slot = (g * 4 + Eoff) * FPS_T + tid;                        \
          const float old = smd[slot];                                          \
          const float dx = vx.E - qx, dy = vy.E - qy, dz = vz.E - qz;           \
          const float d2 = __fadd_rn(__fadd_rn(__fmul_rn(dx, dx),               \
                                               __fmul_rn(dy, dy)),              \
                                     __fmul_rn(dz, dz));                        \
          const float nm = fminf(old, d2);                                      \
          smd[slot] = nm;                                                       \
          const u64 kj = ((u64)__float_as_uint(nm) << 32) |                     \
                         (unsigned)(N_PTS - 1 - vi.E);                          \
          if (kj > nk) nk = kj;                                                 \
        }
        FPS_UPD(x, 0) FPS_UPD(y, 1) FPS_UPD(z, 2) FPS_UPD(w, 3)
#undef FPS_UPD
      }
      ckey = nk;
      cmax = __uint_as_float((unsigned)(nk >> 32));
    }

    // wave max of chunk keys
    u64 k = ckey;
#pragma unroll
    for (int off = 32; off; off >>= 1) {
      const u64 o = __shfl_xor(k, off);
      if (o > k) k = o;
    }
    if (lane == 0) s_wkey[tid >> 6] = k;
    __syncthreads();
    // every wave redundantly reduces the 8 wave keys -> no extra barrier
    u64 kk = s_wkey[lane & 7];
#pragma unroll
    for (int off = 4; off; off >>= 1) {
      const u64 o = __shfl_xor(kk, off);
      if (o > kk) kk = o;
    }
    const int oidx = (N_PTS - 1) - (int)(unsigned)kk;
    qx = cX[oidx]; qy = cY[oidx]; qz = cZ[oidx];
    if (tid == 0) {
      float* orow = out + (size_t)s * ROWF;
      orow[0] = qx; orow[1] = qy; orow[2] = qz;
      float* qrow = qc + s * 3;
      qrow[0] = qx; qrow[1] = qy; qrow[2] = qz;
    }
    __syncthreads();   // protect s_wkey before next step's writes
  }
}

// ---------------------------------------------------------------------------
// 4) KNN top-16 (ties -> lowest index) fused with feature max-pool.
//    One wave per query. Packed u64 (d2_bits<<32 | idx) == lex (d2, idx).
// ---------------------------------------------------------------------------
__global__ __launch_bounds__(256)
void knn_pool_kernel(const float* __restrict__ x,
                     const float* __restrict__ cX, const float* __restrict__ cY,
                     const float* __restrict__ cZ,
                     const float* __restrict__ qc, float* __restrict__ out) {
  const int lane = threadIdx.x & 63;
  const int q = blockIdx.x * 4 + (threadIdx.x >> 6);

  const float qx = qc[q * 3 + 0], qy = qc[q * 3 + 1], qz = qc[q * 3 + 2];

  u64 h[KNN];
#pragma unroll
  for (int k = 0; k < KNN; ++k) h[k] = ~0ULL;

  for (int c = lane; c < N_PTS; c += 64) {
    const float dx = cX[c] - qx, dy = cY[c] - qy, dz = cZ[c] - qz;
    const float d2 = __fadd_rn(__fadd_rn(__fmul_rn(dx, dx), __fmul_rn(dy, dy)),
                               __fmul_rn(dz, dz));
    const u64 e = ((u64)__float_as_uint(d2) << 32) | (unsigned)c;
    if (e < h[KNN - 1]) {
#pragma unroll
      for (int k = KNN - 1; k >= 1; --k) {
        const u64 prev = h[k - 1];
        h[k] = (e < prev) ? prev : ((e < h[k]) ? e : h[k]);
      }
      h[0] = (e < h[0]) ? e : h[0];
    }
  }

  int nbr[KNN];
#pragma unroll
  for (int rr = 0; rr < KNN; ++rr) {
    u64 best = h[0];
#pragma unroll
    for (int off = 32; off; off >>= 1) {
      const u64 o = __shfl_xor(best, off);
      best = (o < best) ? o : best;
    }
    nbr[rr] = (int)(unsigned)(best & 0xffffffffULL);
    if (h[0] == best) {
#pragma unroll
      for (int k = 0; k < KNN - 1; ++k) h[k] = h[k + 1];
      h[KNN - 1] = ~0ULL;
    }
  }

  float a0 = __int_as_float(0xff800000), a1 = a0;
#pragma unroll
  for (int rr = 0; rr < KNN; ++rr) {
    const float* row = x + (size_t)nbr[rr] * ROWF + 3;
    a0 = fmaxf(a0, row[lane]);
    a1 = fmaxf(a1, row[lane + 64]);
  }
  float* orow = out + (size_t)q * ROWF + 3;
  orow[lane] = a0;
  orow[lane + 64] = a1;
}

extern "C" void kernel_launch(void* const* d_in, const int* in_sizes, int n_in,
                              void* d_out, int out_size, void* d_ws, size_t ws_size,
                              hipStream_t stream) {
  const float* x = (const float*)d_in[0];
  float* out = (float*)d_out;

  float* cX   = (float*)d_ws;          // N
  float* cY   = cX + N_PTS;            // N
  float* cZ   = cY + N_PTS;            // N
  float* gX   = cZ + N_PTS;            // N (sorted)
  float* gY   = gX + N_PTS;            // N
  float* gZ   = gY + N_PTS;            // N
  int*   gIdx = (int*)(gZ + N_PTS);    // N
  float* qc   = (float*)(gIdx + N_PTS);// M*3

  hipLaunchKernelGGL(prep_kernel, dim3(16), dim3(1024), 0, stream, x, cX, cY, cZ);
  hipLaunchKernelGGL(sort_kernel, dim3(1), dim3(1024), 0, stream,
                     cX, cY, cZ, gX, gY, gZ, gIdx);
  hipLaunchKernelGGL(fps_kernel, dim3(1), dim3(FPS_T), 0, stream,
                     cX, cY, cZ, gX, gY, gZ, gIdx, out, qc);
  hipLaunchKernelGGL(knn_pool_kernel, dim3(M_OUT / 4), dim3(256), 0, stream,
                     x, cX, cY, cZ, qc, out);
}